// Round 9
// baseline (1938.284 us; speedup 1.0000x reference)
//
#include <hip/hip_runtime.h>
#include <cstdint>
#include <cstddef>

#define DI __device__ __forceinline__

typedef __bf16 bf16_t;
typedef __bf16 bf16x8 __attribute__((ext_vector_type(8)));
typedef float f32x4 __attribute__((ext_vector_type(4)));

static constexpr float SCALE = 0.17677669529663687f;  // 32^-0.5

DI bf16_t f2b(float f) {
  uint32_t u = __builtin_bit_cast(uint32_t, f);
  u += 0x7fffu + ((u >> 16) & 1u);
  return __builtin_bit_cast(bf16_t, (uint16_t)(u >> 16));
}

DI void gld16(const void* g, void* l) {
  __builtin_amdgcn_global_load_lds(
      (const __attribute__((address_space(1))) uint32_t*)g,
      (__attribute__((address_space(3))) uint32_t*)l, 16, 0, 0);
}

// ---------------- weight convert f32 -> bf16 ----------------
__global__ __launch_bounds__(256)
void cvtw(const float* __restrict__ in, bf16_t* __restrict__ out, int n) {
  int i = (blockIdx.x * 256 + threadIdx.x) * 4;
  if (i >= n) return;
  float4 v = *(const float4*)(in + i);
  ushort4 o;
  o.x = __builtin_bit_cast(uint16_t, f2b(v.x));
  o.y = __builtin_bit_cast(uint16_t, f2b(v.y));
  o.z = __builtin_bit_cast(uint16_t, f2b(v.z));
  o.w = __builtin_bit_cast(uint16_t, f2b(v.w));
  *(ushort4*)(out + i) = o;
}

// ---------------- rel-pos bias expand: [16][64][64], pad = -1e30 ----------------
__global__ __launch_bounds__(256)
void bias_pre(const float* __restrict__ rel, float* __restrict__ bf) {
  int idx = blockIdx.x * 256 + threadIdx.x;  // 65536
  int head = idx >> 12, t1 = (idx >> 6) & 63, t2 = idx & 63;
  float v = -1e30f;
  if (t1 < 49 && t2 < 49) {
    int i1 = t1 / 7, j1 = t1 - i1 * 7, i2 = t2 / 7, j2 = t2 - i2 * 7;
    v = rel[((i1 - i2 + 6) * 13 + (j1 - j2 + 6)) * 16 + head];
  }
  bf[idx] = v;
}

// ---------------- LayerNorm, 2 rows per block (R8-verified) ----------------
template<bool WIN>
__global__ __launch_bounds__(256)
void ln_kernel(const float* __restrict__ in, const float* __restrict__ g,
               const float* __restrict__ be, bf16_t* __restrict__ out)
{
  const int tid = threadIdx.x;
  const int r = blockIdx.x * 2 + (tid >> 7);
  const int ti = tid & 127;
  long srow;
  if (WIN) {
    int bw = r / 49, t = r - bw * 49;
    int b = bw >> 6, w = bw & 63;
    int wh = w >> 3, ww = w & 7;
    int i = t / 7, j = t - i * 7;
    int hs = wh * 7 + i + 3; if (hs >= 56) hs -= 56;
    int wsr = ww * 7 + j + 3; if (wsr >= 56) wsr -= 56;
    srow = (long)b * 3136 + hs * 56 + wsr;
  } else {
    srow = r;
  }
  const float4 v = *(const float4*)(in + srow * 512 + ti * 4);
  float s = v.x + v.y + v.z + v.w;
  float sq = v.x * v.x + v.y * v.y + v.z * v.z + v.w * v.w;
#pragma unroll
  for (int m = 1; m < 64; m <<= 1) { s += __shfl_xor(s, m); sq += __shfl_xor(sq, m); }
  __shared__ float ls[4], lq[4];
  const int wv = tid >> 6;
  if ((tid & 63) == 0) { ls[wv] = s; lq[wv] = sq; }
  __syncthreads();
  const int rp = (tid >> 7) * 2;
  s = ls[rp] + ls[rp + 1]; sq = lq[rp] + lq[rp + 1];
  const float mean = s * (1.f / 512.f);
  const float rs = rsqrtf(sq * (1.f / 512.f) - mean * mean + 1e-5f);
  const float4 gg = *(const float4*)(g + ti * 4);
  const float4 bb = *(const float4*)(be + ti * 4);
  ushort4 o;
  o.x = __builtin_bit_cast(uint16_t, f2b((v.x - mean) * rs * gg.x + bb.x));
  o.y = __builtin_bit_cast(uint16_t, f2b((v.y - mean) * rs * gg.y + bb.y));
  o.z = __builtin_bit_cast(uint16_t, f2b((v.z - mean) * rs * gg.z + bb.z));
  o.w = __builtin_bit_cast(uint16_t, f2b((v.w - mean) * rs * gg.w + bb.w));
  *(ushort4*)(out + (long)r * 512 + ti * 4) = o;
}

#define MFMA16(a, b, c) __builtin_amdgcn_mfma_f32_16x16x32_bf16((a), (b), (c), 0, 0, 0)

// ---------------- gemm256: R3-verified persistent 256x256, L2-coherent walk ---
// (Best measured config, 1314 us total.)  Used for QKV (EPI 0) + proj (EPI 1).
template<int EPI>
__global__ __launch_bounds__(512, 2)
void gemm256(const bf16_t* __restrict__ A, const bf16_t* __restrict__ Bw,
             const float* __restrict__ bias, const float* __restrict__ extra,
             void* __restrict__ out0, void* __restrict__ out1v, void* __restrict__ out2v,
             const int K, const int NBN)
{
  __shared__ __align__(128) bf16_t lds[8][8192];
  const int tid = threadIdx.x, lane = tid & 63, wave = tid >> 6;
  const int NT = K >> 6;

  const int xcd = blockIdx.x & 7, j = blockIdx.x >> 3;
  const int G = 32 / NBN;
  if (j >= G * NBN) return;
  const int bmo = j / NBN;
  const int bn = j - bmo * NBN;
  const int m0 = xcd * 49;
  const int tiles = (49 - bmo + G - 1) / G;
  const int ST = tiles * NT;
  const int hEnd = 2 * ST;

  const int srow = tid >> 2, slot = tid & 3;
  const int chunk = slot ^ ((srow >> 1) & 3);
  const size_t rowK = (size_t)128 * K;
  const size_t strideA = (size_t)G * 256 * K;

  const bf16_t* pAs = A + ((size_t)(m0 + bmo) * 256 + srow) * K + chunk * 8;
  const bf16_t* pBs = Bw + ((size_t)bn * 256 + srow) * K + chunk * 8;
  int hA = 0, hB = 0, ktA = 0, hhA = 0, ktB = 0, hhB = 0;

#define STG_A() do { \
    if (hA < hEnd) { \
      const bf16_t* _p = pAs + ktA * 64 + hhA * 32; \
      bf16_t* _l = &lds[(ktA & 1) * 2 + hhA][tid * 8]; \
      gld16(_p, _l); gld16(_p + rowK, _l + 4096); \
      ++hA; hhA ^= 1; \
      if (!hhA) { if (++ktA == NT) { ktA = 0; pAs += strideA; } } \
    } \
  } while (0)

#define STG_B() do { \
    if (hB < hEnd) { \
      const bf16_t* _p = pBs + ktB * 64 + hhB * 32; \
      bf16_t* _l = &lds[4 + (ktB & 1) * 2 + hhB][tid * 8]; \
      gld16(_p, _l); gld16(_p + rowK, _l + 4096); \
      ++hB; hhB ^= 1; \
      if (!hhB) { if (++ktB == NT) ktB = 0; } \
    } \
  } while (0)

  const int fr = lane & 15, fkc = lane >> 4;
  const int wr = wave >> 2, wc = wave & 3;
  const int slotq = (fkc ^ ((fr >> 1) & 3)) << 3;
  const int aoff = (wr * 128 + fr) * 32 + slotq;
  const int boff = (wc * 64 + fr) * 32 + slotq;

  f32x4 acc[8][4] = {};
  bf16x8 af[8], bq[4];

  STG_A(); STG_B(); STG_A(); STG_B(); STG_A(); STG_B(); STG_A();
  asm volatile("s_waitcnt vmcnt(6)");
  __builtin_amdgcn_s_barrier();
  __builtin_amdgcn_sched_barrier(0);

#define PH_SYNC() \
  __builtin_amdgcn_sched_barrier(0); \
  __builtin_amdgcn_s_barrier(); \
  asm volatile("s_waitcnt lgkmcnt(0)"); \
  __builtin_amdgcn_sched_barrier(0); \
  __builtin_amdgcn_s_setprio(1)

#define PH_END() \
  __builtin_amdgcn_s_setprio(0); \
  __builtin_amdgcn_sched_barrier(0); \
  __builtin_amdgcn_s_barrier()

#define MM2(N0, N1) \
  _Pragma("unroll") \
  for (int m = 0; m < 8; ++m) { \
    acc[m][N0] = MFMA16(af[m], bq[N0], acc[m][N0]); \
    acc[m][N1] = MFMA16(af[m], bq[N1], acc[m][N1]); \
  }

#define KTILE(B) do { \
    _Pragma("unroll") \
    for (int m = 0; m < 8; ++m) af[m] = *(const bf16x8*)&lds[(B) * 2][aoff + m * 512]; \
    bq[0] = *(const bf16x8*)&lds[4 + (B) * 2][boff]; \
    bq[1] = *(const bf16x8*)&lds[4 + (B) * 2][boff + 512]; \
    STG_B(); \
    PH_SYNC(); \
    MM2(0, 1); \
    PH_END(); \
    bq[2] = *(const bf16x8*)&lds[4 + (B) * 2][boff + 1024]; \
    bq[3] = *(const bf16x8*)&lds[4 + (B) * 2][boff + 1536]; \
    STG_A(); \
    PH_SYNC(); \
    MM2(2, 3); \
    PH_END(); \
    _Pragma("unroll") \
    for (int m = 0; m < 8; ++m) af[m] = *(const bf16x8*)&lds[(B) * 2 + 1][aoff + m * 512]; \
    bq[0] = *(const bf16x8*)&lds[4 + (B) * 2 + 1][boff]; \
    bq[1] = *(const bf16x8*)&lds[4 + (B) * 2 + 1][boff + 512]; \
    STG_B(); \
    PH_SYNC(); \
    MM2(0, 1); \
    PH_END(); \
    bq[2] = *(const bf16x8*)&lds[4 + (B) * 2 + 1][boff + 1024]; \
    bq[3] = *(const bf16x8*)&lds[4 + (B) * 2 + 1][boff + 1536]; \
    STG_A(); \
    PH_SYNC(); \
    MM2(2, 3); \
    __builtin_amdgcn_s_setprio(0); \
    __builtin_amdgcn_sched_barrier(0); \
    if (sG + 2 < ST) asm volatile("s_waitcnt vmcnt(6)"); \
    else             asm volatile("s_waitcnt vmcnt(0)"); \
    __builtin_amdgcn_s_barrier(); \
    __builtin_amdgcn_sched_barrier(0); \
    ++sG; \
  } while (0)

  int sG = 0;
  int bmC = m0 + bmo;
  const int rq = fkc * 4;
  float bs[4];
#pragma unroll
  for (int n = 0; n < 4; ++n) bs[n] = bias[bn * 256 + wc * 64 + n * 16 + fr];

  for (int t = 0; t < tiles; ++t) {
#pragma unroll 1
    for (int k2 = 0; k2 < NT; k2 += 2) {
      KTILE(0);
      KTILE(1);
    }
#pragma unroll
    for (int m = 0; m < 8; ++m) {
#pragma unroll
      for (int jj4 = 0; jj4 < 4; ++jj4) {
        const int grow = bmC * 256 + wr * 128 + m * 16 + rq + jj4;
        long obase = 0;
        if (EPI == 0) {
          int bwi = grow / 49, t_ = grow - bwi * 49;
          obase = ((long)bwi * 784 + t_) * 32;
        } else {
          int bwi = grow / 49, t_ = grow - bwi * 49;
          int b = bwi >> 6, w = bwi & 63;
          int wh = w >> 3, ww = w & 7;
          int i = t_ / 7, jj = t_ - i * 7;
          int hs = wh * 7 + i + 3; if (hs >= 56) hs -= 56;
          int wsr = ww * 7 + jj + 3; if (wsr >= 56) wsr -= 56;
          obase = ((long)b * 3136 + hs * 56 + wsr) * 512;
        }
#pragma unroll
        for (int n = 0; n < 4; ++n) {
          const int gcol = bn * 256 + wc * 64 + n * 16 + fr;
          float v = acc[m][n][jj4] + bs[n];
          if (EPI == 0) {
            int part = gcol >> 9, head = (gcol >> 5) & 15, d = gcol & 31;
            if (part == 0) v *= SCALE;
            bf16_t* dst = (bf16_t*)(part == 0 ? out0 : (part == 1 ? out1v : out2v));
            dst[obase + (long)head * 1568 + d] = f2b(v);
          } else {
            ((float*)out0)[obase + gcol] = v + extra[obase + gcol];
          }
        }
      }
    }
#pragma unroll
    for (int m = 0; m < 8; ++m)
#pragma unroll
      for (int n = 0; n < 4; ++n) acc[m][n] = (f32x4){0.f, 0.f, 0.f, 0.f};
    bmC += G;
  }
#undef KTILE
#undef MM2
#undef PH_END
#undef PH_SYNC
#undef STG_A
#undef STG_B
}

// ---------------- mlp_fused: GELU-MLP with hidden kept on-CU -----------------
// out = extra + (GELU(A@W1^T + b1)) @ W2^T + b2, A = h2 [100352][512] bf16.
// Eliminates the 822 MB hidden round-trip (R8 post-mortem: traffic, not
// schedule, is the remaining lever).  Per block: 128 M-rows, full N2=512.
// Per hidden-chunk hc (16 x 128): GEMM1 (K=512, BK=32, 16 steps, 3-buf gld16)
// -> bias+GELU -> swizzled ds_write_b16 into HT[4][128x32] -> GEMM2 (4 steps
// of K=32) accumulating acc2[4][8] across all hc.  W2 staged to B22 2x32KB.
// vmcnt ledger (chronological outstanding list, verified):
//   GEMM1 s<=11: vmcnt(2); s12 (+B2k0): 6; s13: 6; s14 (+B2k1): 4.
//   kk loop: vmcnt(0) each; staging issued AFTER the barrier; cross-hc prime
//   at kk=2, forced by kk=3's vmcnt(2).
template<int DUMMY>
__global__ __launch_bounds__(512, 2)
void mlp_fused(const bf16_t* __restrict__ A, const bf16_t* __restrict__ W1,
               const float* __restrict__ b1, const bf16_t* __restrict__ W2,
               const float* __restrict__ b2, const float* __restrict__ extra,
               float* __restrict__ out)
{
  __shared__ __align__(128) bf16_t A3[3][4096];    // 24 KB  [buf][128r x 32k]
  __shared__ __align__(128) bf16_t B13[3][4096];   // 24 KB
  __shared__ __align__(128) bf16_t HT[4][4096];    // 32 KB  [kk][128r x 32k]
  __shared__ __align__(128) bf16_t B22[2][16384];  // 64 KB  [buf][q][512r x 8]
  const int tid = threadIdx.x, lane = tid & 63, wave = tid >> 6;
  const int bm = (blockIdx.x & 7) * 98 + (blockIdx.x >> 3);  // XCD-contig

  // staging (A/B1): row tid>>2, slot tid&3, src chunk = slot^((row>>1)&3)
  const int srow = tid >> 2, slot = tid & 3;
  const int chunk = slot ^ ((srow >> 1) & 3);
  const bf16_t* pA = A + ((size_t)(bm * 128 + srow) * 512) + chunk * 8;

#define STG_B2(HC, KKi, BUF) do { \
    const bf16_t* _w = W2 + (size_t)tid * 2048 + (HC) * 128 + (KKi) * 32; \
    gld16(_w + ((0 ^ ((tid >> 1) & 3)) << 3), &B22[BUF][tid * 8]); \
    gld16(_w + ((1 ^ ((tid >> 1) & 3)) << 3), &B22[BUF][4096 + tid * 8]); \
    gld16(_w + ((2 ^ ((tid >> 1) & 3)) << 3), &B22[BUF][8192 + tid * 8]); \
    gld16(_w + ((3 ^ ((tid >> 1) & 3)) << 3), &B22[BUF][12288 + tid * 8]); \
  } while (0)

  // fragment addressing (proven XOR family)
  const int fr = lane & 15, fkc = lane >> 4;
  const int wr = wave >> 2, wc = wave & 3;          // 2M x 4N for both GEMMs
  const int slotq = (fkc ^ ((fr >> 1) & 3)) << 3;
  const int aoff1 = (wr * 64 + fr) * 32 + slotq;    // + m*512 (A rows / HT rows)
  const int boff1 = (wc * 32 + fr) * 32 + slotq;    // + n*512 (B1 rows)
  const int boff2 = slotq * 512 + (wc * 128 + fr) * 8;  // + n2*128 (B22)
  const int rq = fkc * 4;

  f32x4 acc2[4][8] = {};

  // block prologue: prime hc=0 steps 0,1
  {
    const bf16_t* pB1p = W1 + (size_t)srow * 512 + chunk * 8;
    gld16(pA, &A3[0][tid * 8]);       gld16(pB1p, &B13[0][tid * 8]);
    gld16(pA + 32, &A3[1][tid * 8]);  gld16(pB1p + 32, &B13[1][tid * 8]);
  }
  asm volatile("s_waitcnt vmcnt(2)");
  __builtin_amdgcn_s_barrier();
  __builtin_amdgcn_sched_barrier(0);

#pragma unroll 1
  for (int hc = 0; hc < 16; ++hc) {
    const bf16_t* pB1 = W1 + ((size_t)(hc * 128 + srow) * 512) + chunk * 8;
    f32x4 acc1[4][2] = {};

    // ---- GEMM1: 16 steps, bufs s%3 ----
#pragma unroll
    for (int s = 0; s < 16; ++s) {
      const int b = s % 3;
      bf16x8 af0 = *(const bf16x8*)&A3[b][aoff1];
      bf16x8 af1 = *(const bf16x8*)&A3[b][aoff1 + 512];
      bf16x8 af2 = *(const bf16x8*)&A3[b][aoff1 + 1024];
      bf16x8 af3 = *(const bf16x8*)&A3[b][aoff1 + 1536];
      bf16x8 bq0 = *(const bf16x8*)&B13[b][boff1];
      bf16x8 bq1 = *(const bf16x8*)&B13[b][boff1 + 512];
      if (s < 14) {
        const int tb = (s + 2) % 3;
        gld16(pA + (s + 2) * 32, &A3[tb][tid * 8]);
        gld16(pB1 + (s + 2) * 32, &B13[tb][tid * 8]);
      }
      if (s == 12) STG_B2(hc, 0, 0);
      if (s == 14) STG_B2(hc, 1, 1);
      asm volatile("s_waitcnt lgkmcnt(0)");
      __builtin_amdgcn_sched_barrier(0);
      __builtin_amdgcn_s_setprio(1);
      acc1[0][0] = MFMA16(af0, bq0, acc1[0][0]); acc1[0][1] = MFMA16(af0, bq1, acc1[0][1]);
      acc1[1][0] = MFMA16(af1, bq0, acc1[1][0]); acc1[1][1] = MFMA16(af1, bq1, acc1[1][1]);
      acc1[2][0] = MFMA16(af2, bq0, acc1[2][0]); acc1[2][1] = MFMA16(af2, bq1, acc1[2][1]);
      acc1[3][0] = MFMA16(af3, bq0, acc1[3][0]); acc1[3][1] = MFMA16(af3, bq1, acc1[3][1]);
      __builtin_amdgcn_s_setprio(0);
      __builtin_amdgcn_sched_barrier(0);
      if (s <= 11)      asm volatile("s_waitcnt vmcnt(2)");
      else if (s == 12) asm volatile("s_waitcnt vmcnt(6)");
      else if (s == 13) asm volatile("s_waitcnt vmcnt(6)");
      else if (s == 14) asm volatile("s_waitcnt vmcnt(4)");
      __builtin_amdgcn_s_barrier();
      __builtin_amdgcn_sched_barrier(0);
    }

    // ---- bias + GELU -> HT (swizzled b16 writes; 2-way conflicts = free) ----
    {
      float bsn0 = b1[hc * 128 + wc * 32 + fr];
      float bsn1 = b1[hc * 128 + wc * 32 + 16 + fr];
#pragma unroll
      for (int m = 0; m < 4; ++m)
#pragma unroll
        for (int n = 0; n < 2; ++n)
#pragma unroll
          for (int jj = 0; jj < 4; ++jj) {
            const int rl = wr * 64 + m * 16 + rq + jj;
            float v = acc1[m][n][jj] + (n == 0 ? bsn0 : bsn1);
            float m2 = v * v;
            float z = v * fmaf(0.07135481627f, m2, 1.59576912161f);
            float e = __expf(z);
            float rr = __builtin_amdgcn_rcpf(e + 1.0f);
            const int c = n * 2 + (fr >> 3);
            const int sl = c ^ ((rl >> 1) & 3);
            HT[wc][rl * 32 + (sl << 3) + (fr & 7)] = f2b(fmaf(-v, rr, v));
          }
    }
    asm volatile("s_waitcnt lgkmcnt(0)");
    __builtin_amdgcn_s_barrier();
    __builtin_amdgcn_sched_barrier(0);

    // ---- GEMM2: 4 steps over this hc's K=128 ----
#pragma unroll
    for (int kk = 0; kk < 4; ++kk) {
      const int bb = kk & 1;
      bf16x8 ah0 = *(const bf16x8*)&HT[kk][aoff1];
      bf16x8 ah1 = *(const bf16x8*)&HT[kk][aoff1 + 512];
      bf16x8 ah2 = *(const bf16x8*)&HT[kk][aoff1 + 1024];
      bf16x8 ah3 = *(const bf16x8*)&HT[kk][aoff1 + 1536];
      asm volatile("s_waitcnt lgkmcnt(0)");
      __builtin_amdgcn_sched_barrier(0);
      __builtin_amdgcn_s_setprio(1);
#pragma unroll
      for (int n2 = 0; n2 < 8; ++n2) {
        bf16x8 bw = *(const bf16x8*)&B22[bb][boff2 + n2 * 128];
        asm volatile("s_waitcnt lgkmcnt(0)");
        acc2[0][n2] = MFMA16(ah0, bw, acc2[0][n2]);
        acc2[1][n2] = MFMA16(ah1, bw, acc2[1][n2]);
        acc2[2][n2] = MFMA16(ah2, bw, acc2[2][n2]);
        acc2[3][n2] = MFMA16(ah3, bw, acc2[3][n2]);
      }
      __builtin_amdgcn_s_setprio(0);
      __builtin_amdgcn_sched_barrier(0);
      if (kk == 3 && hc < 15) asm volatile("s_waitcnt vmcnt(2)");
      else                    asm volatile("s_waitcnt vmcnt(0)");
      __builtin_amdgcn_s_barrier();
      __builtin_amdgcn_sched_barrier(0);
      if (kk == 0) STG_B2(hc, 2, 0);
      if (kk == 1) STG_B2(hc, 3, 1);
      if (kk == 2 && hc < 15) {
        const bf16_t* pB1n = W1 + ((size_t)((hc + 1) * 128 + srow) * 512) + chunk * 8;
        gld16(pA, &A3[0][tid * 8]);       gld16(pB1n, &B13[0][tid * 8]);
        gld16(pA + 32, &A3[1][tid * 8]);  gld16(pB1n + 32, &B13[1][tid * 8]);
      }
    }
  }

  // ---- epilogue: out = acc2 + b2 + extra (f32, 64B-contiguous per 1/4-wave)
  float bs2[8];
#pragma unroll
  for (int n2 = 0; n2 < 8; ++n2) bs2[n2] = b2[wc * 128 + n2 * 16 + fr];
#pragma unroll
  for (int m = 0; m < 4; ++m)
#pragma unroll
    for (int jj = 0; jj < 4; ++jj) {
      const long base = ((long)bm * 128 + wr * 64 + m * 16 + rq + jj) * 512;
#pragma unroll
      for (int n2 = 0; n2 < 8; ++n2) {
        const int gcol = wc * 128 + n2 * 16 + fr;
        out[base + gcol] = acc2[m][n2][jj] + bs2[n2] + extra[base + gcol];
      }
    }
#undef STG_B2
}

// ---------------- attention: one block per (window, head) ----------------
__global__ __launch_bounds__(256)
void attn_kernel(const bf16_t* __restrict__ qb, const bf16_t* __restrict__ kb,
                 const bf16_t* __restrict__ vb, const float* __restrict__ biasf,
                 bf16_t* __restrict__ aout)
{
  __shared__ bf16_t Q[64 * 32];
  __shared__ bf16_t Kl[64 * 32];
  __shared__ bf16_t Vt[32 * 64];
  __shared__ bf16_t Pl[4][16 * 64];
  const int bid = blockIdx.x;
  const int bw = bid >> 4, head = bid & 15;
  const int tid = threadIdx.x, lane = tid & 63, wave = tid >> 6;
  {
    uint4 z = {0u, 0u, 0u, 0u};
    *(uint4*)&Q[tid * 8] = z;
    *(uint4*)&Kl[tid * 8] = z;
    *(uint4*)&Vt[tid * 8] = z;
  }
  __syncthreads();
  const bf16_t* qsrc = qb + (long)bid * (49 * 32);
  const bf16_t* ksrc = kb + (long)bid * (49 * 32);
  const bf16_t* vsrc = vb + (long)bid * (49 * 32);
  if (tid < 196) {
    *(uint4*)&Q[tid * 8] = *(const uint4*)(qsrc + tid * 8);
    *(uint4*)&Kl[tid * 8] = *(const uint4*)(ksrc + tid * 8);
  }
  for (int e = tid; e < 1568; e += 256) {
    int t = e >> 5, d = e & 31;
    Vt[d * 64 + t] = vsrc[e];
  }
  __syncthreads();
  const int fr = lane & 15, fk = (lane >> 4) * 8, rq = (lane >> 4) * 4;
  bf16x8 aq = *(const bf16x8*)&Q[(wave * 16 + fr) * 32 + fk];
  f32x4 s[4];
#pragma unroll
  for (int n = 0; n < 4; ++n) {
    bf16x8 bk = *(const bf16x8*)&Kl[(n * 16 + fr) * 32 + fk];
    f32x4 z = {0.f, 0.f, 0.f, 0.f};
    s[n] = __builtin_amdgcn_mfma_f32_16x16x32_bf16(aq, bk, z, 0, 0, 0);
  }
  const int w = bw & 63;
  const bool wh7 = ((w >> 3) == 7), ww7 = ((w & 7) == 7);
  const float* bh = biasf + head * 4096;
#pragma unroll
  for (int j = 0; j < 4; ++j) {
    const int row = wave * 16 + rq + j;
    int i1 = row / 7, j1 = row - i1 * 7;
    bool b1h = wh7 && (i1 >= 4), b1w = ww7 && (j1 >= 4);
    float pv[4];
    float mx = -3.0e38f;
#pragma unroll
    for (int n = 0; n < 4; ++n) {
      const int col = n * 16 + fr;
      float v = s[n][j] + bh[row * 64 + col];
      if (wh7 || ww7) {
        int i2 = col / 7, j2 = col - i2 * 7;
        bool b2h = wh7 && (i2 >= 4), b2w = ww7 && (j2 >= 4);
        if ((b1h != b2h) || (b1w != b2w)) v -= 100.f;
      }
      pv[n] = v;
      mx = fmaxf(mx, v);
    }
#pragma unroll
    for (int msk = 1; msk < 16; msk <<= 1) mx = fmaxf(mx, __shfl_xor(mx, msk));
    float sm = 0.f;
#pragma unroll
    for (int n = 0; n < 4; ++n) { pv[n] = __expf(pv[n] - mx); sm += pv[n]; }
#pragma unroll
    for (int msk = 1; msk < 16; msk <<= 1) sm += __shfl_xor(sm, msk);
    const float inv = 1.f / sm;
#pragma unroll
    for (int n = 0; n < 4; ++n)
      Pl[wave][(rq + j) * 64 + n * 16 + fr] = f2b(pv[n] * inv);
  }
  __syncthreads();
  f32x4 o[2] = {};
#pragma unroll
  for (int kk = 0; kk < 2; ++kk) {
    bf16x8 pa = *(const bf16x8*)&Pl[wave][fr * 64 + kk * 32 + fk];
#pragma unroll
    for (int dt = 0; dt < 2; ++dt) {
      bf16x8 vv = *(const bf16x8*)&Vt[(dt * 16 + fr) * 64 + kk * 32 + fk];
      o[dt] = __builtin_amdgcn_mfma_f32_16x16x32_bf16(pa, vv, o[dt], 0, 0, 0);
    }
  }
#pragma unroll
  for (int j = 0; j < 4; ++j) {
    const int t1 = wave * 16 + rq + j;
    if (t1 < 49) {
      bf16_t* dst = aout + ((long)bw * 49 + t1) * 512 + head * 32;
      dst[fr] = f2b(o[0][j]);
      dst[16 + fr] = f2b(o[1][j]);
    }
  }
}

// ---------------- launch ----------------
extern "C" void kernel_launch(void* const* d_in, const int* in_sizes, int n_in,
                              void* d_out, int out_size, void* d_ws, size_t ws_size,
                              hipStream_t stream)
{
  const float* x      = (const float*)d_in[0];
  const float* n1g    = (const float*)d_in[1];
  const float* n1b    = (const float*)d_in[2];
  const float* qkv_w  = (const float*)d_in[3];
  const float* qkv_b  = (const float*)d_in[4];
  const float* rel    = (const float*)d_in[5];
  const float* proj_w = (const float*)d_in[6];
  const float* proj_b = (const float*)d_in[7];
  const float* n2g    = (const float*)d_in[8];
  const float* n2b    = (const float*)d_in[9];
  const float* w1     = (const float*)d_in[10];
  const float* b1     = (const float*)d_in[11];
  const float* w2     = (const float*)d_in[12];
  const float* b2     = (const float*)d_in[13];

  char* ws = (char*)d_ws;
  bf16_t* Wqkv  = (bf16_t*)(ws + 0);          // 1536*512*2 = 1572864
  bf16_t* Wproj = (bf16_t*)(ws + 1572864);    // 512*512*2  = 524288
  bf16_t* Wm1   = (bf16_t*)(ws + 2097152);    // 2048*512*2 = 2097152
  bf16_t* Wm2   = (bf16_t*)(ws + 4194304);    // 512*2048*2 = 2097152
  float*  biasf = (float*)(ws + 6291456);     // 16*64*64*4 = 1048576
  const size_t ABYTES = (size_t)100352 * 512 * 2;  // 102760448
  const size_t P1 = 8388608;
  const size_t P2 = P1 + ABYTES + 1048576;
  bf16_t* xw      = (bf16_t*)(ws + P1);
  bf16_t* qbuf    = (bf16_t*)(ws + P2);
  bf16_t* kbuf    = (bf16_t*)(ws + P2 + ABYTES);
  bf16_t* vbuf    = (bf16_t*)(ws + P2 + 2 * ABYTES);
  bf16_t* attnout = xw;       // reuse after QKV gemm consumed xw
  bf16_t* h2      = xw;       // reuse after proj consumed attnout

  cvtw<<<768, 256, 0, stream>>>(qkv_w, Wqkv, 1536 * 512);
  cvtw<<<256, 256, 0, stream>>>(proj_w, Wproj, 512 * 512);
  cvtw<<<1024, 256, 0, stream>>>(w1, Wm1, 2048 * 512);
  cvtw<<<1024, 256, 0, stream>>>(w2, Wm2, 512 * 2048);
  bias_pre<<<256, 256, 0, stream>>>(rel, biasf);

  ln_kernel<true><<<50176, 256, 0, stream>>>(x, n1g, n1b, xw);
  gemm256<0><<<256, 512, 0, stream>>>(xw, Wqkv, qkv_b, nullptr,
                                      qbuf, kbuf, vbuf, 512, 6);
  attn_kernel<<<32768, 256, 0, stream>>>(qbuf, kbuf, vbuf, biasf, attnout);
  gemm256<1><<<256, 512, 0, stream>>>(attnout, Wproj, proj_b, x,
                                      d_out, nullptr, nullptr, 512, 2);
  ln_kernel<false><<<50176, 256, 0, stream>>>((const float*)d_out, n2g, n2b, h2);
  mlp_fused<0><<<784, 512, 0, stream>>>(h2, Wm1, b1, Wm2, b2,
                                        (const float*)d_out, (float*)d_out);
}